// Round 7
// baseline (164.913 us; speedup 1.0000x reference)
//
#include <hip/hip_runtime.h>
#include <math.h>

// Dims: B=2, H=256, W=256, C=64, heads=8, dh=64, hd=512, dim_out=64.
// Inputs fp32, output fp32. Internals bf16 + MFMA.
//
// attn[b,h,i,j] = (Wk_i^T G[b] Wq_j)/(||k_i|| ||q_j||)*rescale[h],
// G[b] = Xd^T Xd (Gram of 2x2-avg-pooled input).
// out = x@W_eff[b] + bproj + dwconv2(gelu(dwconv1(x@W_pos + bc1d)))
// W_eff[b] = Wv @ blockdiag_h(attn_h^T) @ Wproj,  W_pos = Wv @ Wc1d.
//
// R1: occupancy restructure. R2: norms folded into attn blocks.
// R3: attn MFMA-ized (split-bf16 hi+lo). R4: frag-friendly weight tables.
// R5 (reverted): atomics Gram + conv1-fused pmain both regressed.
// R6: k_final conv2->regs + stage-overlays-sm (LDS 34816); k_mid2 LDS 37-38K.
// R7: k_mid2 -> 512-thread blocks. Attn: 8 waves, wave owns (m-band, nt-pair)
//     -> 2 waves/SIMD latency hiding in the 16-block tail. conv1: 2 strips
//     per thread, up to 8 waves x 4 blocks/CU. Math order: only norm/softmax
//     fp32 re-association.

typedef unsigned short u16;
typedef unsigned int u32;
typedef __attribute__((ext_vector_type(8))) short short8;
typedef __attribute__((ext_vector_type(4))) float f32x4;

__device__ __forceinline__ float bf2f(u16 h) { return __uint_as_float(((u32)h) << 16); }
__device__ __forceinline__ u16 f2bf(float f) {
    u32 u = __float_as_uint(f);
    return (u16)((u + 0x7fffu + ((u >> 16) & 1u)) >> 16);
}
__device__ __forceinline__ float rbf(float f) { return bf2f(f2bf(f)); }
__device__ __forceinline__ u32 pk2(float lo, float hi) {
    return (u32)f2bf(lo) | ((u32)f2bf(hi) << 16);
}
__device__ __forceinline__ void unpack8(uint4 v, float* f) {
    u32 a[4] = {v.x, v.y, v.z, v.w};
#pragma unroll
    for (int i = 0; i < 4; ++i) {
        f[2 * i]     = __uint_as_float(a[i] << 16);
        f[2 * i + 1] = __uint_as_float(a[i] & 0xffff0000u);
    }
}
__device__ __forceinline__ float gelu_exact(float v) {
    return 0.5f * v * (1.f + erff(v * 0.70710678118654752f));
}
// split f32 -> bf16 hi + bf16 lo (captures ~16 mantissa bits)
__device__ __forceinline__ void splitbf(float g, short& hi, short& lo) {
    u16 hb = f2bf(g);
    hi = (short)hb;
    lo = (short)f2bf(g - bf2f(hb));
}

// ---------------------------------------------------------------------------
// K1: blocks 0..322 weight fp32->bf16 (+ transposed wqT/wkT/wpT tables);
//     323..386 Wpos = Wv@Wc1d (+ wposT bf16 table); 387..898 pool + Gram
//     partials + xb emit (half-row per block).
__global__ __launch_bounds__(256) void k_front(
    const float* __restrict__ x,
    const float* __restrict__ wq_f, const float* __restrict__ wk_f,
    const float* __restrict__ wv_f, const float* __restrict__ rs_f,
    const float* __restrict__ wp_f, const float* __restrict__ bp_f,
    const float* __restrict__ wc_f, const float* __restrict__ bc_f,
    const float* __restrict__ p1_f, const float* __restrict__ p2_f,
    u32* __restrict__ wb32, u16* __restrict__ wqT, u16* __restrict__ wkT,
    u16* __restrict__ wpT, float* __restrict__ Wpos, u16* __restrict__ wposT,
    u16* __restrict__ xb, float* __restrict__ partials) {
    __shared__ float xvs[64 * 68];
    int blk = blockIdx.x;
    int t = threadIdx.x;
    if (blk < 323) {
        u32 pid = (u32)blk * 256u + t;
        if (pid < 82564u) {
            const float* src; u32 p;
            if      (pid < 16384u) { src = wq_f; p = pid; }
            else if (pid < 32768u) { src = wk_f; p = pid - 16384u; }
            else if (pid < 49152u) { src = wv_f; p = pid - 32768u; }
            else if (pid < 49156u) { src = rs_f; p = pid - 49152u; }
            else if (pid < 65540u) { src = wp_f; p = pid - 49156u; }
            else if (pid < 65572u) { src = bp_f; p = pid - 65540u; }
            else if (pid < 81956u) { src = wc_f; p = pid - 65572u; }
            else if (pid < 81988u) { src = bc_f; p = pid - 81956u; }
            else if (pid < 82276u) { src = p1_f; p = pid - 81988u; }
            else                   { src = p2_f; p = pid - 82276u; }
            wb32[pid] = (u32)f2bf(src[2 * p]) | ((u32)f2bf(src[2 * p + 1]) << 16);
            if (pid < 32768u) {               // wq / wk transposed tables
                u16* dstT = (pid < 16384u) ? wqT : wkT;
                u32 e0 = 2u * (pid & 16383u);
                u32 c = e0 >> 9, j = e0 & 511u;
                dstT[j * 64 + c]       = f2bf(src[e0]);
                dstT[(j + 1) * 64 + c] = f2bf(src[e0 + 1]);
            } else if (pid >= 49156u && pid < 65540u) {   // wp transposed
                u32 e0 = 2u * (pid - 49156u);
                u32 ip = e0 >> 6, o = e0 & 63u;
                u32 base = (ip >> 6) * 4096u + (ip & 63u);
                wpT[base + o * 64]       = f2bf(src[e0]);
                wpT[base + (o + 1) * 64] = f2bf(src[e0 + 1]);
            }
        }
    } else if (blk < 387) {
        int c = blk - 323;                    // 0..63, one Wv row per block
        int o = t & 63, ch = t >> 6;          // ch = k-chunk (one per wave)
        const float* wvr = wv_f + c * 512 + ch * 128;
        const float* wcr = wc_f + (size_t)(ch * 128) * 64 + o;
        float s = 0.f;
        for (int kk = 0; kk < 128; ++kk)
            s += rbf(wvr[kk]) * rbf(wcr[(size_t)kk * 64]);
        xvs[ch * 64 + o] = s;
        __syncthreads();
        if (t < 64) {
            float v = (xvs[t] + xvs[64 + t]) + (xvs[128 + t] + xvs[192 + t]);
            Wpos[c * 64 + t] = v;
            wposT[t * 64 + c] = f2bf(v);      // [o][k] bf16 fragment table
        }
    } else {
        int gb = blk - 387;                   // 0..511
        int b = gb >> 8, sub = gb & 255;
        int py = sub >> 1, half = sub & 1;
        const size_t rowbase = (size_t)(b * 256 + 2 * py) * 16384 + (size_t)half * 8192;
#pragma unroll
        for (int i2 = 0; i2 < 4; ++i2) {
            int u = t + 256 * i2;
            int P = u >> 4, cq = u & 15;      // P: pooled col within half (0..63)
            size_t o0 = rowbase + (size_t)(2 * P) * 64 + cq * 4;
            float4 a0 = *(const float4*)(x + o0);
            float4 a1 = *(const float4*)(x + o0 + 64);
            float4 a2 = *(const float4*)(x + o0 + 16384);
            float4 a3 = *(const float4*)(x + o0 + 16384 + 64);
            *(uint2*)(xb + o0)              = make_uint2(pk2(a0.x, a0.y), pk2(a0.z, a0.w));
            *(uint2*)(xb + o0 + 64)         = make_uint2(pk2(a1.x, a1.y), pk2(a1.z, a1.w));
            *(uint2*)(xb + o0 + 16384)      = make_uint2(pk2(a2.x, a2.y), pk2(a2.z, a2.w));
            *(uint2*)(xb + o0 + 16384 + 64) = make_uint2(pk2(a3.x, a3.y), pk2(a3.z, a3.w));
            float4 s;
            s.x = 0.25f * (a0.x + a1.x + a2.x + a3.x);
            s.y = 0.25f * (a0.y + a1.y + a2.y + a3.y);
            s.z = 0.25f * (a0.z + a1.z + a2.z + a3.z);
            s.w = 0.25f * (a0.w + a1.w + a2.w + a3.w);
            *(float4*)(&xvs[P * 68 + cq * 4]) = s;
        }
        __syncthreads();
        int r0 = (t >> 4) << 2, c0 = (t & 15) << 2;
        float acc[4][4] = {{0.f}};
        for (int P = 0; P < 64; ++P) {
            float4 av = *(const float4*)(&xvs[P * 68 + r0]);
            float4 bv = *(const float4*)(&xvs[P * 68 + c0]);
            float ar[4] = {av.x, av.y, av.z, av.w};
            float br[4] = {bv.x, bv.y, bv.z, bv.w};
#pragma unroll
            for (int i = 0; i < 4; ++i)
#pragma unroll
                for (int j = 0; j < 4; ++j)
                    acc[i][j] += ar[i] * br[j];
        }
        float* outp = partials + (size_t)gb * 4096;
#pragma unroll
        for (int i = 0; i < 4; ++i)
            *(float4*)(&outp[(r0 + i) * 64 + c0]) =
                make_float4(acc[i][0], acc[i][1], acc[i][2], acc[i][3]);
    }
}

// ---------------------------------------------------------------------------
// K2: blocks 0..127 Gram reduce into 4-chunk G4 (+Weff zero);
//     128..1151 pmain (MFMA matvec, 128 px per block, wposT frag loads).
__global__ __launch_bounds__(256) void k_mid1(
    const float* __restrict__ partials, float* __restrict__ G4, float* __restrict__ Weff,
    const u16* __restrict__ xb, const u16* __restrict__ wposT,
    const u16* __restrict__ bc1d, u16* __restrict__ pbuf) {
    __shared__ u16 sm[128 * 72];
    int blk = blockIdx.x;
    int t = threadIdx.x;
    if (blk < 128) {
        int gid = blk * 256 + t;              // 0..32767
        int e = gid & 4095, ch = (gid >> 12) & 3, b = gid >> 14;
        const float* p0 = partials + ((size_t)(b * 256 + ch * 64)) * 4096 + e;
        float s = 0.f;
        for (int p = 0; p < 64; ++p)
            s += p0[(size_t)p * 4096];
        G4[gid] = s;
        if (gid < 8192) Weff[gid] = 0.f;
        return;
    }
    int pb = blk - 128;                       // 0..1023
    int lane = t & 63, wv = t >> 6;
    int col = lane & 15, quad = lane >> 4;

    short8 bf[2][4];
#pragma unroll
    for (int kh = 0; kh < 2; ++kh)
#pragma unroll
        for (int nt = 0; nt < 4; ++nt)
            bf[kh][nt] = *(const short8*)(&wposT[(nt * 16 + col) * 64 + kh * 32 + quad * 8]);
    float bias[4];
#pragma unroll
    for (int nt = 0; nt < 4; ++nt) bias[nt] = bf2f(bc1d[nt * 16 + col]);

    size_t base = (size_t)pb * 128;
#pragma unroll
    for (int g = 0; g < 2; ++g) {
        int P0 = wv * 32 + g * 16;
        const short8* ap = (const short8*)(xb + (base + P0 + col) * 64);
        short8 a0 = ap[quad];
        short8 a1 = ap[4 + quad];
#pragma unroll
        for (int nt = 0; nt < 4; ++nt) {
            f32x4 acc = {0.f, 0.f, 0.f, 0.f};
            acc = __builtin_amdgcn_mfma_f32_16x16x32_bf16(a0, bf[0][nt], acc, 0, 0, 0);
            acc = __builtin_amdgcn_mfma_f32_16x16x32_bf16(a1, bf[1][nt], acc, 0, 0, 0);
#pragma unroll
            for (int r = 0; r < 4; ++r)
                sm[(P0 + quad * 4 + r) * 72 + nt * 16 + col] = f2bf(acc[r] + bias[nt]);
        }
    }
    __syncthreads();
#pragma unroll
    for (int k = 0; k < 4; ++k) {
        int linear = k * 256 + t;
        int px = linear >> 3, oct = linear & 7;
        uint4 v = *(const uint4*)(&sm[px * 72 + oct * 8]);
        *(uint4*)(pbuf + (base + px) * 64 + oct * 8) = v;
    }
}

// ---------------------------------------------------------------------------
// K3: 512-thread blocks. Blocks 0..15 attn (8 waves: wave = (m-band, nt-pair));
//     16..1039 conv1 (2 strips/thread).
// Attn LDS (38400 B):
//   [0..18432)      Ghi[64][72]u16 @0, Glo @9216; after A-frag reg load ->
//                   RG f32[64][68] (Lraw/attn).
//   [18432..35840)  RA f32[64][68]: Tk -> Tq -> P.
//   [35840..37888)  scr f32[512]: norm partials (8 groups).
//   [37888..38144)  nkA f32[64];  [38144..38400) nqA f32[64].
__global__ __launch_bounds__(512) void k_mid2(
    const u16* __restrict__ wqT, const u16* __restrict__ wkT,
    const u16* __restrict__ wpT, const u16* __restrict__ wvb,
    const u16* __restrict__ rsb,
    const float* __restrict__ G4, float* __restrict__ Weff,
    const u16* __restrict__ pbuf, const u16* __restrict__ wpe1,
    u16* __restrict__ tbuf) {
    __shared__ __align__(16) char shm[38400];
    int blk = blockIdx.x, t = threadIdx.x;
    if (blk < 16) {
        u16*   GhiL = (u16*)shm;
        u16*   GloL = (u16*)(shm + 9216);
        float* RG   = (float*)shm;
        float* RA   = (float*)(shm + 18432);
        float* scr  = (float*)(shm + 35840);
        float* nkA  = (float*)(shm + 37888);
        float* nqA  = (float*)(shm + 38144);
        int b = blk >> 3, h = blk & 7;
        int lane = t & 63;
        int mb = (t >> 6) & 3;                // m-band (16 rows)
        int np = t >> 8;                      // nt-pair: nt in {2np, 2np+1}
        int lr = lane & 15, lq = lane >> 4;
        {   // P0: G = sum of 4 G4 chunks; split -> Ghi/Glo (8 elems/thread)
            int base = t * 8;
            int row = base >> 6, col = base & 63;
            const float* Gb = G4 + (size_t)b * 16384;
            short8 hi8, lo8;
#pragma unroll
            for (int q = 0; q < 8; ++q) {
                int e = base + q;
                float g = (Gb[e] + Gb[4096 + e]) + (Gb[8192 + e] + Gb[12288 + e]);
                short hh, ll; splitbf(g, hh, ll);
                hi8[q] = hh; lo8[q] = ll;
            }
            *(short8*)(&GhiL[row * 72 + col]) = hi8;
            *(short8*)(&GloL[row * 72 + col]) = lo8;
        }
        __syncthreads();
        // G A-frags (band mb) held in registers; G's LDS copy dead after this
        short8 ahi[2], alo[2];
#pragma unroll
        for (int ks = 0; ks < 2; ++ks) {
            ahi[ks] = *(const short8*)(&GhiL[(mb * 16 + lr) * 72 + ks * 32 + lq * 8]);
            alo[ks] = *(const short8*)(&GloL[(mb * 16 + lr) * 72 + ks * 32 + lq * 8]);
        }
        {   // P1: Tk = G@Wk_h -> RA (this wave: 2 nt tiles)
#pragma unroll
            for (int ni = 0; ni < 2; ++ni) {
                int nt = np * 2 + ni;
                f32x4 acc = {0.f, 0.f, 0.f, 0.f};
#pragma unroll
                for (int ks = 0; ks < 2; ++ks) {
                    short8 bv = *(const short8*)(&wkT[(h * 64 + nt * 16 + lr) * 64 + ks * 32 + lq * 8]);
                    acc = __builtin_amdgcn_mfma_f32_16x16x32_bf16(ahi[ks], bv, acc, 0, 0, 0);
                    acc = __builtin_amdgcn_mfma_f32_16x16x32_bf16(alo[ks], bv, acc, 0, 0, 0);
                }
#pragma unroll
                for (int r = 0; r < 4; ++r)
                    RA[(mb * 16 + lq * 4 + r) * 68 + nt * 16 + lr] = acc[r];
            }
        }
        __syncthreads();
        {   // P2: nk partials (Wk .* Tk), 8 groups x 8 rows -> scr
            int ci = t & 63, grp = t >> 6;
            const u16* wr = wkT + (h * 64 + ci) * 64 + grp * 8;
            float s = 0.f;
#pragma unroll
            for (int cc = 0; cc < 8; ++cc)
                s += bf2f(wr[cc]) * RA[(grp * 8 + cc) * 68 + ci];
            scr[grp * 64 + ci] = s;
        }
        __syncthreads();
        // P3: nk combine; Tq = G@Wq_h -> RA (overwrites Tk)
        if (t < 64) {
            float s = ((scr[t] + scr[64 + t]) + (scr[128 + t] + scr[192 + t])) +
                      ((scr[256 + t] + scr[320 + t]) + (scr[384 + t] + scr[448 + t]));
            nkA[t] = fmaxf(sqrtf(fmaxf(s, 0.f)), 1e-12f);
        }
        {
#pragma unroll
            for (int ni = 0; ni < 2; ++ni) {
                int nt = np * 2 + ni;
                f32x4 acc = {0.f, 0.f, 0.f, 0.f};
#pragma unroll
                for (int ks = 0; ks < 2; ++ks) {
                    short8 bv = *(const short8*)(&wqT[(h * 64 + nt * 16 + lr) * 64 + ks * 32 + lq * 8]);
                    acc = __builtin_amdgcn_mfma_f32_16x16x32_bf16(ahi[ks], bv, acc, 0, 0, 0);
                    acc = __builtin_amdgcn_mfma_f32_16x16x32_bf16(alo[ks], bv, acc, 0, 0, 0);
                }
#pragma unroll
                for (int r = 0; r < 4; ++r)
                    RA[(mb * 16 + lq * 4 + r) * 68 + nt * 16 + lr] = acc[r];
            }
        }
        __syncthreads();
        {   // P4: nq partials (Wq .* Tq) -> scr ; Lraw = Wk^T @ Tq -> RG
            int ci = t & 63, grp = t >> 6;
            const u16* wr = wqT + (h * 64 + ci) * 64 + grp * 8;
            float s = 0.f;
#pragma unroll
            for (int cc = 0; cc < 8; ++cc)
                s += bf2f(wr[cc]) * RA[(grp * 8 + cc) * 68 + ci];
            scr[grp * 64 + ci] = s;

            short8 ak[2];
#pragma unroll
            for (int ks = 0; ks < 2; ++ks)
                ak[ks] = *(const short8*)(&wkT[(h * 64 + mb * 16 + lr) * 64 + ks * 32 + lq * 8]);
#pragma unroll
            for (int ni = 0; ni < 2; ++ni) {
                int nt = np * 2 + ni;
                f32x4 acc = {0.f, 0.f, 0.f, 0.f};
#pragma unroll
                for (int ks = 0; ks < 2; ++ks) {
                    short8 bhi, blo;
#pragma unroll
                    for (int jj = 0; jj < 8; ++jj) {
                        short h16, l16;
                        splitbf(RA[(ks * 32 + lq * 8 + jj) * 68 + nt * 16 + lr], h16, l16);
                        bhi[jj] = h16; blo[jj] = l16;
                    }
                    acc = __builtin_amdgcn_mfma_f32_16x16x32_bf16(ak[ks], bhi, acc, 0, 0, 0);
                    acc = __builtin_amdgcn_mfma_f32_16x16x32_bf16(ak[ks], blo, acc, 0, 0, 0);
                }
#pragma unroll
                for (int r = 0; r < 4; ++r)
                    RG[(mb * 16 + lq * 4 + r) * 68 + nt * 16 + lr] = acc[r];
            }
        }
        __syncthreads();
        // P5: nq combine
        if (t < 64) {
            float s = ((scr[t] + scr[64 + t]) + (scr[128 + t] + scr[192 + t])) +
                      ((scr[256 + t] + scr[320 + t]) + (scr[384 + t] + scr[448 + t]));
            nqA[t] = fmaxf(sqrtf(fmaxf(s, 0.f)), 1e-12f);
        }
        __syncthreads();
        {   // P6: scale + softmax (Lraw in RG) -> attn in place (8 lanes/row)
            int i = t >> 3, jq = t & 7, j0 = jq * 8;
            float L[8];
#pragma unroll
            for (int q = 0; q < 2; ++q) {
                float4 lv = *(const float4*)(&RG[i * 68 + j0 + 4 * q]);
                L[4 * q] = lv.x; L[4 * q + 1] = lv.y;
                L[4 * q + 2] = lv.z; L[4 * q + 3] = lv.w;
            }
            float rs = bf2f(rsb[h]);
            float nki = nkA[i];
            float nqv[8];
#pragma unroll
            for (int jj = 0; jj < 8; ++jj) nqv[jj] = nqA[j0 + jj];
            float m = -1e30f;
#pragma unroll
            for (int jj = 0; jj < 8; ++jj) {
                L[jj] = L[jj] * rs / (nki * nqv[jj]);
                m = fmaxf(m, L[jj]);
            }
            m = fmaxf(m, __shfl_xor(m, 1));
            m = fmaxf(m, __shfl_xor(m, 2));
            m = fmaxf(m, __shfl_xor(m, 4));
            float s = 0.f;
#pragma unroll
            for (int jj = 0; jj < 8; ++jj) {
                L[jj] = __expf(L[jj] - m);
                s += L[jj];
            }
            s += __shfl_xor(s, 1);
            s += __shfl_xor(s, 2);
            s += __shfl_xor(s, 4);
            float inv = 1.f / s;
#pragma unroll
            for (int q = 0; q < 2; ++q)
                *(float4*)(&RG[i * 68 + j0 + 4 * q]) =
                    make_float4(L[4 * q] * inv, L[4 * q + 1] * inv,
                                L[4 * q + 2] * inv, L[4 * q + 3] * inv);
        }
        __syncthreads();
        {   // P7: P = attn^T @ Wproj_h -> RA (overwrites Tq)
            short8 phi[2], plo[2];
#pragma unroll
            for (int ks = 0; ks < 2; ++ks) {
                short8 hi, lo;
#pragma unroll
                for (int jj = 0; jj < 8; ++jj) {
                    short h16, l16;
                    splitbf(RG[(ks * 32 + lq * 8 + jj) * 68 + mb * 16 + lr], h16, l16);
                    hi[jj] = h16; lo[jj] = l16;
                }
                phi[ks] = hi; plo[ks] = lo;
            }
#pragma unroll
            for (int ni = 0; ni < 2; ++ni) {
                int nt = np * 2 + ni;
                f32x4 acc = {0.f, 0.f, 0.f, 0.f};
#pragma unroll
                for (int ks = 0; ks < 2; ++ks) {
                    short8 bv = *(const short8*)(&wpT[h * 4096 + (nt * 16 + lr) * 64 + ks * 32 + lq * 8]);
                    acc = __builtin_amdgcn_mfma_f32_16x16x32_bf16(phi[ks], bv, acc, 0, 0, 0);
                    acc = __builtin_amdgcn_mfma_f32_16x16x32_bf16(plo[ks], bv, acc, 0, 0, 0);
                }
#pragma unroll
                for (int r = 0; r < 4; ++r)
                    RA[(mb * 16 + lq * 4 + r) * 68 + nt * 16 + lr] = acc[r];
            }
        }
        __syncthreads();
        {   // P8: Weff += Wv_h @ P -> atomicAdd
            short8 av[2];
#pragma unroll
            for (int ks = 0; ks < 2; ++ks)
                av[ks] = *(const short8*)(&wvb[(mb * 16 + lr) * 512 + h * 64 + ks * 32 + lq * 8]);
            float* W = Weff + b * 4096;
#pragma unroll
            for (int ni = 0; ni < 2; ++ni) {
                int nt = np * 2 + ni;
                f32x4 acc = {0.f, 0.f, 0.f, 0.f};
#pragma unroll
                for (int ks = 0; ks < 2; ++ks) {
                    short8 bhi, blo;
#pragma unroll
                    for (int jj = 0; jj < 8; ++jj) {
                        short h16, l16;
                        splitbf(RA[(ks * 32 + lq * 8 + jj) * 68 + nt * 16 + lr], h16, l16);
                        bhi[jj] = h16; blo[jj] = l16;
                    }
                    acc = __builtin_amdgcn_mfma_f32_16x16x32_bf16(av[ks], bhi, acc, 0, 0, 0);
                    acc = __builtin_amdgcn_mfma_f32_16x16x32_bf16(av[ks], blo, acc, 0, 0, 0);
                }
#pragma unroll
                for (int r = 0; r < 4; ++r)
                    atomicAdd(&W[(mb * 16 + lq * 4 + r) * 64 + nt * 16 + lr], acc[r]);
            }
        }
        return;
    }
    // ---- conv1 (512 threads: 2 strips/thread), cb = blk - 16 ----
    u16* sm = (u16*)shm;                       // 204*72 u16 = 29376 B
    int cb = blk - 16;
    int b  = cb >> 9;
    int ty = (cb >> 3) & 63;
    int tx = cb & 7;
    int gy0 = ty * 4, gx0 = tx * 32;

    for (int i = t; i < 1632; i += 512) {
        int px = i >> 3, ch = i & 7;
        int hy = px / 34, hx = px - hy * 34;
        int gy = gy0 + hy - 1, gx = gx0 + hx - 1;
        uint4 v = make_uint4(0, 0, 0, 0);
        if ((unsigned)gy < 256u && (unsigned)gx < 256u)
            v = *(const uint4*)(pbuf + ((size_t)((b << 16) + (gy << 8) + gx)) * 64 + ch * 8);
        *(uint4*)(&sm[px * 72 + ch * 8]) = v;
    }
    int oct = t & 7;
    float w[8][9];
#pragma unroll
    for (int j = 0; j < 8; ++j)
#pragma unroll
        for (int k = 0; k < 9; ++k) w[j][k] = bf2f(wpe1[(oct * 8 + j) * 9 + k]);
    __syncthreads();

#pragma unroll
    for (int s = 0; s < 2; ++s) {
        int lp = (t >> 3) + s * 64;
        int ly = lp >> 5, lx = lp & 31;
        float acc[8] = {0.f, 0.f, 0.f, 0.f, 0.f, 0.f, 0.f, 0.f};
#pragma unroll
        for (int dy = 0; dy < 3; ++dy)
#pragma unroll
            for (int dx = 0; dx < 3; ++dx) {
                int hp = (ly + dy) * 34 + lx + dx;
                uint4 v = *(const uint4*)(&sm[hp * 72 + oct * 8]);
                float f[8];
                unpack8(v, f);
                int tap = dy * 3 + dx;
#pragma unroll
                for (int j = 0; j < 8; ++j) acc[j] += f[j] * w[j][tap];
            }
        u32 pk[4];
#pragma unroll
        for (int q = 0; q < 4; ++q)
            pk[q] = pk2(gelu_exact(acc[2 * q]), gelu_exact(acc[2 * q + 1]));
        size_t gpix = (size_t)(b << 16) + ((size_t)(gy0 + ly) << 8) + gx0 + lx;
        *(uint4*)(tbuf + gpix * 64 + oct * 8) = make_uint4(pk[0], pk[1], pk[2], pk[3]);
    }
}

// ---------------------------------------------------------------------------
// K4: out = xb @ Weff[b] + bproj + dwconv3x3(tbuf, Wpe2).
// conv2 -> packed-bf16 regs; f32 stage overlays dead sm (LDS 34816 total).
__global__ __launch_bounds__(256) void k_final(const u16* __restrict__ xb,
                                               const u16* __restrict__ tbuf,
                                               const float* __restrict__ Weff,
                                               const u16* __restrict__ wpe2,
                                               const u16* __restrict__ bproj,
                                               float* __restrict__ out) {
    __shared__ __align__(16) char shmf[34816];
    u16*   sm    = (u16*)shmf;               // [204][72] halo (dead after conv)
    float* stage = (float*)shmf;             // [128][68] overlays sm
    int t = threadIdx.x;
    int blk = blockIdx.x;
    int b  = blk >> 9;
    int ty = (blk >> 3) & 63;
    int tx = blk & 7;
    int gy0 = ty * 4, gx0 = tx * 32;

    for (int i = t; i < 1632; i += 256) {
        int px = i >> 3, ch = i & 7;
        int hy = px / 34, hx = px - hy * 34;
        int gy = gy0 + hy - 1, gx = gx0 + hx - 1;
        uint4 v = make_uint4(0, 0, 0, 0);
        if ((unsigned)gy < 256u && (unsigned)gx < 256u)
            v = *(const uint4*)(tbuf + ((size_t)((b << 16) + (gy << 8) + gx)) * 64 + ch * 8);
        *(uint4*)(&sm[px * 72 + ch * 8]) = v;
    }
    int oct = t & 7;
    u32 racc[4][4];
    {
        float w[8][9];
#pragma unroll
        for (int j = 0; j < 8; ++j)
#pragma unroll
            for (int k = 0; k < 9; ++k) w[j][k] = bf2f(wpe2[(oct * 8 + j) * 9 + k]);
        __syncthreads();
#pragma unroll
        for (int s = 0; s < 4; ++s) {
            int lp = (t >> 3) + s * 32;
            int ly = lp >> 5, lx = lp & 31;
            float acc[8] = {0.f, 0.f, 0.f, 0.f, 0.f, 0.f, 0.f, 0.f};
#pragma unroll
            for (int dy = 0; dy < 3; ++dy)
#pragma unroll
                for (int dx = 0; dx < 3; ++dx) {
                    int hp = (ly + dy) * 34 + lx + dx;
                    uint4 v = *(const uint4*)(&sm[hp * 72 + oct * 8]);
                    float f[8];
                    unpack8(v, f);
                    int tap = dy * 3 + dx;
#pragma unroll
                    for (int j = 0; j < 8; ++j) acc[j] += f[j] * w[j][tap];
                }
#pragma unroll
            for (int q = 0; q < 4; ++q)
                racc[s][q] = pk2(acc[2 * q], acc[2 * q + 1]);
        }
    }
    __syncthreads();                          // all conv reads of sm done
#pragma unroll
    for (int s = 0; s < 4; ++s) {
        int lp = (t >> 3) + s * 32;
#pragma unroll
        for (int q = 0; q < 4; ++q) {
            stage[lp * 68 + oct * 8 + 2 * q]     = __uint_as_float(racc[s][q] << 16);
            stage[lp * 68 + oct * 8 + 2 * q + 1] = __uint_as_float(racc[s][q] & 0xffff0000u);
        }
    }
    __syncthreads();                          // stage fully written

    int lane = t & 63, wv = t >> 6;
    int col = lane & 15, quad = lane >> 4;
    const float* W = Weff + b * 4096;
    short8 bf[2][4];
#pragma unroll
    for (int kh = 0; kh < 2; ++kh)
#pragma unroll
        for (int nt = 0; nt < 4; ++nt) {
            short8 v;
#pragma unroll
            for (int j = 0; j < 8; ++j)
                v[j] = (short)f2bf(W[(kh * 32 + quad * 8 + j) * 64 + nt * 16 + col]);
            bf[kh][nt] = v;
        }
    float bias[4];
#pragma unroll
    for (int nt = 0; nt < 4; ++nt) bias[nt] = bf2f(bproj[nt * 16 + col]);

#pragma unroll
    for (int g = 0; g < 2; ++g) {
        int grp = wv * 2 + g;
        int ly = grp >> 1;
        int lxb = (grp & 1) * 16;
        size_t rowpix = (size_t)(b << 16) + ((size_t)(gy0 + ly) << 8) + gx0;
        const short8* ap = (const short8*)(xb + (rowpix + lxb + col) * 64);
        short8 a0 = ap[quad];
        short8 a1 = ap[4 + quad];
#pragma unroll
        for (int nt = 0; nt < 4; ++nt) {
            f32x4 acc = {0.f, 0.f, 0.f, 0.f};
            acc = __builtin_amdgcn_mfma_f32_16x16x32_bf16(a0, bf[0][nt], acc, 0, 0, 0);
            acc = __builtin_amdgcn_mfma_f32_16x16x32_bf16(a1, bf[1][nt], acc, 0, 0, 0);
#pragma unroll
            for (int r = 0; r < 4; ++r) {
                int lp = ly * 32 + lxb + quad * 4 + r;
                stage[lp * 68 + nt * 16 + col] += acc[r] + bias[nt];
            }
        }
    }
    __syncthreads();

#pragma unroll
    for (int k = 0; k < 8; ++k) {
        int linear = k * 256 + t;
        int px = linear >> 4, c4 = linear & 15;
        int ly = px >> 5, lx = px & 31;
        float4 v = *(const float4*)(&stage[px * 68 + c4 * 4]);
        size_t gpix = (size_t)(b << 16) + ((size_t)(gy0 + ly) << 8) + gx0 + lx;
        *(float4*)(out + gpix * 64 + c4 * 4) = v;
    }
}

// ---------------------------------------------------------------------------
extern "C" void kernel_launch(void* const* d_in, const int* in_sizes, int n_in,
                              void* d_out, int out_size, void* d_ws, size_t ws_size,
                              hipStream_t stream) {
    const float* x = (const float*)d_in[0];
    float* out = (float*)d_out;

    char* w = (char*)d_ws;
    size_t off = 0;
    auto alloc = [&](size_t bytes) -> void* {
        void* p = w + off;
        off += (bytes + 255) & ~(size_t)255;
        return p;
    };
    u16* xb = (u16*)alloc((size_t)16777216 * 2);
    u16* wb = (u16*)alloc((size_t)165128 * 2);
    u16* wqb = wb;
    u16* wkb = wqb + 32768;
    u16* wvb = wkb + 32768;
    u16* rsb = wvb + 32768;
    u16* wpb = rsb + 8;
    u16* bpb = wpb + 32768;
    u16* wcb = bpb + 64;
    u16* bcb = wcb + 32768;
    u16* p1b = bcb + 64;
    u16* p2b = p1b + 576;
    (void)wcb; (void)wqb; (void)wkb; (void)wpb;

    u16* wqT   = (u16*)alloc((size_t)32768 * 2);
    u16* wkT   = (u16*)alloc((size_t)32768 * 2);
    u16* wpT   = (u16*)alloc((size_t)32768 * 2);
    u16* wposT = (u16*)alloc((size_t)4096 * 2);

    float* partials = (float*)alloc((size_t)512 * 4096 * 4);
    float* G4       = (float*)alloc((size_t)2 * 4 * 4096 * 4);
    float* Weff     = (float*)alloc((size_t)2 * 4096 * 4);
    float* Wpos     = (float*)alloc((size_t)4096 * 4);
    u16*   pbuf     = (u16*)alloc((size_t)2 * 65536 * 64 * 2);
    u16*   tbuf     = (u16*)alloc((size_t)2 * 65536 * 64 * 2);

    hipLaunchKernelGGL(k_front, dim3(899), dim3(256), 0, stream,
                       x,
                       (const float*)d_in[1], (const float*)d_in[2], (const float*)d_in[3],
                       (const float*)d_in[4], (const float*)d_in[5], (const float*)d_in[6],
                       (const float*)d_in[7], (const float*)d_in[8], (const float*)d_in[9],
                       (const float*)d_in[10],
                       (u32*)wb, wqT, wkT, wpT, Wpos, wposT, xb, partials);
    hipLaunchKernelGGL(k_mid1, dim3(1152), dim3(256), 0, stream,
                       partials, G4, Weff, xb, wposT, bcb, pbuf);
    hipLaunchKernelGGL(k_mid2, dim3(1040), dim3(512), 0, stream,
                       wqT, wkT, wpT, wvb, rsb, G4, Weff, pbuf, p1b, tbuf);
    hipLaunchKernelGGL(k_final, dim3(1024), dim3(256), 0, stream,
                       xb, tbuf, Weff, p2b, bpb, out);
}

// Round 8
// 155.433 us; speedup vs baseline: 1.0610x; 1.0610x over previous
//
#include <hip/hip_runtime.h>
#include <math.h>

// Dims: B=2, H=256, W=256, C=64, heads=8, dh=64, hd=512, dim_out=64.
// Inputs fp32, output fp32. Internals bf16 + MFMA.
//
// attn[b,h,i,j] = (Wk_i^T G[b] Wq_j)/(||k_i|| ||q_j||)*rescale[h],
// G[b] = Xd^T Xd (Gram of 2x2-avg-pooled input).
// out = x@W_eff[b] + bproj + dwconv2(gelu(dwconv1(x@W_pos + bc1d)))
// W_eff[b] = Wv @ blockdiag_h(attn_h^T) @ Wproj,  W_pos = Wv @ Wc1d.
//
// R1: occupancy restructure. R2: norms folded into attn blocks.
// R3: attn MFMA-ized (split-bf16 hi+lo). R4: frag-friendly weight tables.
// R5/R6/R7 (reverted): atomics Gram, fused pmain, LDS time-share, 512-thr
//   k_mid2 all regressed. Base = R4 exactly.
// R8: attn tail 9 phases -> 6. nk/nq = MFMA diagonal tiles of Wk^T@Tk /
//   Wq^T@Tq computed alongside Lraw (shared A-frags); VALU dot phases and
//   serial t<64 combines deleted; sqrt moved into softmax (same values).

typedef unsigned short u16;
typedef unsigned int u32;
typedef __attribute__((ext_vector_type(8))) short short8;
typedef __attribute__((ext_vector_type(4))) float f32x4;

__device__ __forceinline__ float bf2f(u16 h) { return __uint_as_float(((u32)h) << 16); }
__device__ __forceinline__ u16 f2bf(float f) {
    u32 u = __float_as_uint(f);
    return (u16)((u + 0x7fffu + ((u >> 16) & 1u)) >> 16);
}
__device__ __forceinline__ float rbf(float f) { return bf2f(f2bf(f)); }
__device__ __forceinline__ u32 pk2(float lo, float hi) {
    return (u32)f2bf(lo) | ((u32)f2bf(hi) << 16);
}
__device__ __forceinline__ void unpack8(uint4 v, float* f) {
    u32 a[4] = {v.x, v.y, v.z, v.w};
#pragma unroll
    for (int i = 0; i < 4; ++i) {
        f[2 * i]     = __uint_as_float(a[i] << 16);
        f[2 * i + 1] = __uint_as_float(a[i] & 0xffff0000u);
    }
}
__device__ __forceinline__ float gelu_exact(float v) {
    return 0.5f * v * (1.f + erff(v * 0.70710678118654752f));
}
// split f32 -> bf16 hi + bf16 lo (captures ~16 mantissa bits)
__device__ __forceinline__ void splitbf(float g, short& hi, short& lo) {
    u16 hb = f2bf(g);
    hi = (short)hb;
    lo = (short)f2bf(g - bf2f(hb));
}

// ---------------------------------------------------------------------------
// K1: blocks 0..322 weight fp32->bf16 (+ transposed wqT/wkT/wpT tables);
//     323..386 Wpos = Wv@Wc1d; 387..898 pool+Gram partials + xb emit.
__global__ __launch_bounds__(256) void k_front(
    const float* __restrict__ x,
    const float* __restrict__ wq_f, const float* __restrict__ wk_f,
    const float* __restrict__ wv_f, const float* __restrict__ rs_f,
    const float* __restrict__ wp_f, const float* __restrict__ bp_f,
    const float* __restrict__ wc_f, const float* __restrict__ bc_f,
    const float* __restrict__ p1_f, const float* __restrict__ p2_f,
    u32* __restrict__ wb32, u16* __restrict__ wqT, u16* __restrict__ wkT,
    u16* __restrict__ wpT, float* __restrict__ Wpos,
    u16* __restrict__ xb, float* __restrict__ partials) {
    __shared__ float xvs[64 * 68];
    int blk = blockIdx.x;
    int t = threadIdx.x;
    if (blk < 323) {
        u32 pid = (u32)blk * 256u + t;
        if (pid < 82564u) {
            const float* src; u32 p;
            if      (pid < 16384u) { src = wq_f; p = pid; }
            else if (pid < 32768u) { src = wk_f; p = pid - 16384u; }
            else if (pid < 49152u) { src = wv_f; p = pid - 32768u; }
            else if (pid < 49156u) { src = rs_f; p = pid - 49152u; }
            else if (pid < 65540u) { src = wp_f; p = pid - 49156u; }
            else if (pid < 65572u) { src = bp_f; p = pid - 65540u; }
            else if (pid < 81956u) { src = wc_f; p = pid - 65572u; }
            else if (pid < 81988u) { src = bc_f; p = pid - 81956u; }
            else if (pid < 82276u) { src = p1_f; p = pid - 81988u; }
            else                   { src = p2_f; p = pid - 82276u; }
            wb32[pid] = (u32)f2bf(src[2 * p]) | ((u32)f2bf(src[2 * p + 1]) << 16);
            if (pid < 32768u) {               // wq / wk transposed tables
                u16* dstT = (pid < 16384u) ? wqT : wkT;
                u32 e0 = 2u * (pid & 16383u);
                u32 c = e0 >> 9, j = e0 & 511u;
                dstT[j * 64 + c]       = f2bf(src[e0]);
                dstT[(j + 1) * 64 + c] = f2bf(src[e0 + 1]);
            } else if (pid >= 49156u && pid < 65540u) {   // wp transposed
                u32 e0 = 2u * (pid - 49156u);
                u32 ip = e0 >> 6, o = e0 & 63u;
                u32 base = (ip >> 6) * 4096u + (ip & 63u);
                wpT[base + o * 64]       = f2bf(src[e0]);
                wpT[base + (o + 1) * 64] = f2bf(src[e0 + 1]);
            }
        }
    } else if (blk < 387) {
        int c = blk - 323;                    // 0..63, one Wv row per block
        int o = t & 63, ch = t >> 6;          // ch = k-chunk (one per wave)
        const float* wvr = wv_f + c * 512 + ch * 128;
        const float* wcr = wc_f + (size_t)(ch * 128) * 64 + o;
        float s = 0.f;
        for (int kk = 0; kk < 128; ++kk)
            s += rbf(wvr[kk]) * rbf(wcr[(size_t)kk * 64]);
        xvs[ch * 64 + o] = s;
        __syncthreads();
        if (t < 64)
            Wpos[c * 64 + t] = (xvs[t] + xvs[64 + t]) + (xvs[128 + t] + xvs[192 + t]);
    } else {
        int gb = blk - 387;                   // 0..511
        int b = gb >> 8, sub = gb & 255;
        int py = sub >> 1, half = sub & 1;
        const size_t rowbase = (size_t)(b * 256 + 2 * py) * 16384 + (size_t)half * 8192;
#pragma unroll
        for (int i2 = 0; i2 < 4; ++i2) {
            int u = t + 256 * i2;
            int P = u >> 4, cq = u & 15;      // P: pooled col within half (0..63)
            size_t o0 = rowbase + (size_t)(2 * P) * 64 + cq * 4;
            float4 a0 = *(const float4*)(x + o0);
            float4 a1 = *(const float4*)(x + o0 + 64);
            float4 a2 = *(const float4*)(x + o0 + 16384);
            float4 a3 = *(const float4*)(x + o0 + 16384 + 64);
            *(uint2*)(xb + o0)              = make_uint2(pk2(a0.x, a0.y), pk2(a0.z, a0.w));
            *(uint2*)(xb + o0 + 64)         = make_uint2(pk2(a1.x, a1.y), pk2(a1.z, a1.w));
            *(uint2*)(xb + o0 + 16384)      = make_uint2(pk2(a2.x, a2.y), pk2(a2.z, a2.w));
            *(uint2*)(xb + o0 + 16384 + 64) = make_uint2(pk2(a3.x, a3.y), pk2(a3.z, a3.w));
            float4 s;
            s.x = 0.25f * (a0.x + a1.x + a2.x + a3.x);
            s.y = 0.25f * (a0.y + a1.y + a2.y + a3.y);
            s.z = 0.25f * (a0.z + a1.z + a2.z + a3.z);
            s.w = 0.25f * (a0.w + a1.w + a2.w + a3.w);
            *(float4*)(&xvs[P * 68 + cq * 4]) = s;
        }
        __syncthreads();
        int r0 = (t >> 4) << 2, c0 = (t & 15) << 2;
        float acc[4][4] = {{0.f}};
        for (int P = 0; P < 64; ++P) {
            float4 av = *(const float4*)(&xvs[P * 68 + r0]);
            float4 bv = *(const float4*)(&xvs[P * 68 + c0]);
            float ar[4] = {av.x, av.y, av.z, av.w};
            float br[4] = {bv.x, bv.y, bv.z, bv.w};
#pragma unroll
            for (int i = 0; i < 4; ++i)
#pragma unroll
                for (int j = 0; j < 4; ++j)
                    acc[i][j] += ar[i] * br[j];
        }
        float* outp = partials + (size_t)gb * 4096;
#pragma unroll
        for (int i = 0; i < 4; ++i)
            *(float4*)(&outp[(r0 + i) * 64 + c0]) =
                make_float4(acc[i][0], acc[i][1], acc[i][2], acc[i][3]);
    }
}

// ---------------------------------------------------------------------------
// K2: blocks 0..127 Gram reduce into 4-chunk G4 (+Weff zero);
//     128..1151 pmain (MFMA matvec, 128 px per block).
__global__ __launch_bounds__(256) void k_mid1(
    const float* __restrict__ partials, float* __restrict__ G4, float* __restrict__ Weff,
    const u16* __restrict__ xb, const float* __restrict__ Wpos,
    const u16* __restrict__ bc1d, u16* __restrict__ pbuf) {
    __shared__ u16 sm[128 * 72];
    int blk = blockIdx.x;
    int t = threadIdx.x;
    if (blk < 128) {
        int gid = blk * 256 + t;              // 0..32767
        int e = gid & 4095, ch = (gid >> 12) & 3, b = gid >> 14;
        const float* p0 = partials + ((size_t)(b * 256 + ch * 64)) * 4096 + e;
        float s = 0.f;
        for (int p = 0; p < 64; ++p)
            s += p0[(size_t)p * 4096];
        G4[gid] = s;
        if (gid < 8192) Weff[gid] = 0.f;
        return;
    }
    int pb = blk - 128;                       // 0..1023
    int lane = t & 63, wv = t >> 6;
    int col = lane & 15, quad = lane >> 4;

    short8 bf[2][4];
#pragma unroll
    for (int kh = 0; kh < 2; ++kh)
#pragma unroll
        for (int nt = 0; nt < 4; ++nt) {
            short8 v;
#pragma unroll
            for (int j = 0; j < 8; ++j)
                v[j] = (short)f2bf(Wpos[(kh * 32 + quad * 8 + j) * 64 + nt * 16 + col]);
            bf[kh][nt] = v;
        }
    float bias[4];
#pragma unroll
    for (int nt = 0; nt < 4; ++nt) bias[nt] = bf2f(bc1d[nt * 16 + col]);

    size_t base = (size_t)pb * 128;
#pragma unroll
    for (int g = 0; g < 2; ++g) {
        int P0 = wv * 32 + g * 16;
        const short8* ap = (const short8*)(xb + (base + P0 + col) * 64);
        short8 a0 = ap[quad];
        short8 a1 = ap[4 + quad];
#pragma unroll
        for (int nt = 0; nt < 4; ++nt) {
            f32x4 acc = {0.f, 0.f, 0.f, 0.f};
            acc = __builtin_amdgcn_mfma_f32_16x16x32_bf16(a0, bf[0][nt], acc, 0, 0, 0);
            acc = __builtin_amdgcn_mfma_f32_16x16x32_bf16(a1, bf[1][nt], acc, 0, 0, 0);
#pragma unroll
            for (int r = 0; r < 4; ++r)
                sm[(P0 + quad * 4 + r) * 72 + nt * 16 + col] = f2bf(acc[r] + bias[nt]);
        }
    }
    __syncthreads();
#pragma unroll
    for (int k = 0; k < 4; ++k) {
        int linear = k * 256 + t;
        int px = linear >> 3, oct = linear & 7;
        uint4 v = *(const uint4*)(&sm[px * 72 + oct * 8]);
        *(uint4*)(pbuf + (base + px) * 64 + oct * 8) = v;
    }
}

// ---------------------------------------------------------------------------
// K3: blocks 0..15 attn (6-phase MFMA); 16..1039 conv1 (R4 proven body).
// Attn LDS (53248 B exactly):
//   [0..18432)      Ghi[64][72]u16 @0, Glo @9216; after phase 1 -> RG
//                   f32[64][68] (Lraw/attn).
//   [18432..35840)  RA f32[64][68]: Tk; later P.
//   [35840..53248)  RB f32[64][68]: Tq; pads col64=nk^2 raw, col65=nq^2 raw.
__global__ __launch_bounds__(256) void k_mid2(
    const u16* __restrict__ wqT, const u16* __restrict__ wkT,
    const u16* __restrict__ wpT, const u16* __restrict__ wvb,
    const u16* __restrict__ rsb,
    const float* __restrict__ G4, float* __restrict__ Weff,
    const u16* __restrict__ pbuf, const u16* __restrict__ wpe1, u16* __restrict__ tbuf) {
    __shared__ __align__(16) char shm[53248];
    int blk = blockIdx.x, t = threadIdx.x;
    if (blk < 16) {
        u16*   GhiL = (u16*)shm;
        u16*   GloL = (u16*)(shm + 9216);
        float* RG   = (float*)shm;
        float* RA   = (float*)(shm + 18432);
        float* RB   = (float*)(shm + 35840);
        int b = blk >> 3, h = blk & 7;
        int lane = t & 63, w = t >> 6;        // w = wave = m-band (16 rows)
        int lr = lane & 15, lq = lane >> 4;
        {   // P0: G = sum of 4 G4 chunks; split -> Ghi/Glo (row-major)
            int base = t * 16;
            int row = base >> 6, col = base & 63;
            const float* Gb = G4 + (size_t)b * 16384;
#pragma unroll
            for (int half = 0; half < 2; ++half) {
                short8 hi8, lo8;
#pragma unroll
                for (int q = 0; q < 8; ++q) {
                    int e = base + half * 8 + q;
                    float g = (Gb[e] + Gb[4096 + e]) + (Gb[8192 + e] + Gb[12288 + e]);
                    short hh, ll; splitbf(g, hh, ll);
                    hi8[q] = hh; lo8[q] = ll;
                }
                *(short8*)(&GhiL[row * 72 + col + half * 8]) = hi8;
                *(short8*)(&GloL[row * 72 + col + half * 8]) = lo8;
            }
        }
        __syncthreads();
        {   // P1: Tk = G@Wk_h -> RA ; Tq = G@Wq_h -> RB.
            short8 ahi[2], alo[2];
#pragma unroll
            for (int ks = 0; ks < 2; ++ks) {
                ahi[ks] = *(const short8*)(&GhiL[(w * 16 + lr) * 72 + ks * 32 + lq * 8]);
                alo[ks] = *(const short8*)(&GloL[(w * 16 + lr) * 72 + ks * 32 + lq * 8]);
            }
#pragma unroll
            for (int sel = 0; sel < 2; ++sel) {
                const u16* WT = sel ? wqT : wkT;
                float* outp = sel ? RB : RA;
#pragma unroll
                for (int nt = 0; nt < 4; ++nt) {
                    f32x4 acc = {0.f, 0.f, 0.f, 0.f};
#pragma unroll
                    for (int ks = 0; ks < 2; ++ks) {
                        short8 bv = *(const short8*)(&WT[(h * 64 + nt * 16 + lr) * 64 + ks * 32 + lq * 8]);
                        acc = __builtin_amdgcn_mfma_f32_16x16x32_bf16(ahi[ks], bv, acc, 0, 0, 0);
                        acc = __builtin_amdgcn_mfma_f32_16x16x32_bf16(alo[ks], bv, acc, 0, 0, 0);
                    }
#pragma unroll
                    for (int r = 0; r < 4; ++r)
                        outp[(w * 16 + lq * 4 + r) * 68 + nt * 16 + lr] = acc[r];
                }
            }
        }
        __syncthreads();
        {   // P2: Lraw = Wk^T@Tq -> RG; nk^2 = diag(Wk^T@Tk) -> RB col64;
            //     nq^2 = diag(Wq^T@Tq) -> RB col65. Shared A-frags.
            short8 ak[2], aq[2];
#pragma unroll
            for (int ks = 0; ks < 2; ++ks) {
                ak[ks] = *(const short8*)(&wkT[(h * 64 + w * 16 + lr) * 64 + ks * 32 + lq * 8]);
                aq[ks] = *(const short8*)(&wqT[(h * 64 + w * 16 + lr) * 64 + ks * 32 + lq * 8]);
            }
            {   // diagK: B from Tk (nt = w tile only)
                short8 bhi[2], blo[2];
#pragma unroll
                for (int ks = 0; ks < 2; ++ks) {
                    short8 hi, lo;
#pragma unroll
                    for (int jj = 0; jj < 8; ++jj) {
                        short h16, l16;
                        splitbf(RA[(ks * 32 + lq * 8 + jj) * 68 + w * 16 + lr], h16, l16);
                        hi[jj] = h16; lo[jj] = l16;
                    }
                    bhi[ks] = hi; blo[ks] = lo;
                }
                f32x4 akk = {0.f, 0.f, 0.f, 0.f};
#pragma unroll
                for (int ks = 0; ks < 2; ++ks) {
                    akk = __builtin_amdgcn_mfma_f32_16x16x32_bf16(ak[ks], bhi[ks], akk, 0, 0, 0);
                    akk = __builtin_amdgcn_mfma_f32_16x16x32_bf16(ak[ks], blo[ks], akk, 0, 0, 0);
                }
#pragma unroll
                for (int r = 0; r < 4; ++r)
                    if (lr == lq * 4 + r)
                        RB[(w * 16 + lr) * 68 + 64] = akk[r];
            }
#pragma unroll
            for (int nt = 0; nt < 4; ++nt) {  // Lraw (all nt) + diagQ (nt==w)
                short8 bhi[2], blo[2];
#pragma unroll
                for (int ks = 0; ks < 2; ++ks) {
                    short8 hi, lo;
#pragma unroll
                    for (int jj = 0; jj < 8; ++jj) {
                        short h16, l16;
                        splitbf(RB[(ks * 32 + lq * 8 + jj) * 68 + nt * 16 + lr], h16, l16);
                        hi[jj] = h16; lo[jj] = l16;
                    }
                    bhi[ks] = hi; blo[ks] = lo;
                }
                f32x4 acc = {0.f, 0.f, 0.f, 0.f};
#pragma unroll
                for (int ks = 0; ks < 2; ++ks) {
                    acc = __builtin_amdgcn_mfma_f32_16x16x32_bf16(ak[ks], bhi[ks], acc, 0, 0, 0);
                    acc = __builtin_amdgcn_mfma_f32_16x16x32_bf16(ak[ks], blo[ks], acc, 0, 0, 0);
                }
#pragma unroll
                for (int r = 0; r < 4; ++r)
                    RG[(w * 16 + lq * 4 + r) * 68 + nt * 16 + lr] = acc[r];
                if (nt == w) {
                    f32x4 aqq = {0.f, 0.f, 0.f, 0.f};
#pragma unroll
                    for (int ks = 0; ks < 2; ++ks) {
                        aqq = __builtin_amdgcn_mfma_f32_16x16x32_bf16(aq[ks], bhi[ks], aqq, 0, 0, 0);
                        aqq = __builtin_amdgcn_mfma_f32_16x16x32_bf16(aq[ks], blo[ks], aqq, 0, 0, 0);
                    }
#pragma unroll
                    for (int r = 0; r < 4; ++r)
                        if (lr == lq * 4 + r)
                            RB[(w * 16 + lr) * 68 + 65] = aqq[r];
                }
            }
        }
        __syncthreads();
        {   // P3: scale + softmax (Lraw in RG) -> attn in place
            int i = t >> 2, jq = t & 3, j0 = jq * 16;
            float L[16];
#pragma unroll
            for (int q = 0; q < 4; ++q) {
                float4 lv = *(const float4*)(&RG[i * 68 + j0 + 4 * q]);
                L[4 * q] = lv.x; L[4 * q + 1] = lv.y;
                L[4 * q + 2] = lv.z; L[4 * q + 3] = lv.w;
            }
            float rs = bf2f(rsb[h]);
            float nki = fmaxf(sqrtf(fmaxf(RB[i * 68 + 64], 0.f)), 1e-12f);
            float nqv[16];
#pragma unroll
            for (int jj = 0; jj < 16; ++jj)
                nqv[jj] = fmaxf(sqrtf(fmaxf(RB[(j0 + jj) * 68 + 65], 0.f)), 1e-12f);
            float m = -1e30f;
#pragma unroll
            for (int jj = 0; jj < 16; ++jj) {
                L[jj] = L[jj] * rs / (nki * nqv[jj]);
                m = fmaxf(m, L[jj]);
            }
            m = fmaxf(m, __shfl_xor(m, 1));
            m = fmaxf(m, __shfl_xor(m, 2));
            float s = 0.f;
#pragma unroll
            for (int jj = 0; jj < 16; ++jj) {
                L[jj] = __expf(L[jj] - m);
                s += L[jj];
            }
            s += __shfl_xor(s, 1);
            s += __shfl_xor(s, 2);
            float inv = 1.f / s;
#pragma unroll
            for (int q = 0; q < 4; ++q)
                *(float4*)(&RG[i * 68 + j0 + 4 * q]) =
                    make_float4(L[4 * q] * inv, L[4 * q + 1] * inv,
                                L[4 * q + 2] * inv, L[4 * q + 3] * inv);
        }
        __syncthreads();
        {   // P4: P = attn^T @ Wproj_h -> RA (Tk dead)
            short8 phi[2], plo[2];
#pragma unroll
            for (int ks = 0; ks < 2; ++ks) {
                short8 hi, lo;
#pragma unroll
                for (int jj = 0; jj < 8; ++jj) {
                    short h16, l16;
                    splitbf(RG[(ks * 32 + lq * 8 + jj) * 68 + w * 16 + lr], h16, l16);
                    hi[jj] = h16; lo[jj] = l16;
                }
                phi[ks] = hi; plo[ks] = lo;
            }
#pragma unroll
            for (int nt = 0; nt < 4; ++nt) {
                f32x4 acc = {0.f, 0.f, 0.f, 0.f};
#pragma unroll
                for (int ks = 0; ks < 2; ++ks) {
                    short8 bv = *(const short8*)(&wpT[h * 4096 + (nt * 16 + lr) * 64 + ks * 32 + lq * 8]);
                    acc = __builtin_amdgcn_mfma_f32_16x16x32_bf16(phi[ks], bv, acc, 0, 0, 0);
                    acc = __builtin_amdgcn_mfma_f32_16x16x32_bf16(plo[ks], bv, acc, 0, 0, 0);
                }
#pragma unroll
                for (int r = 0; r < 4; ++r)
                    RA[(w * 16 + lq * 4 + r) * 68 + nt * 16 + lr] = acc[r];
            }
        }
        __syncthreads();
        {   // P5: Weff += Wv_h @ P -> atomicAdd
            short8 av[2];
#pragma unroll
            for (int ks = 0; ks < 2; ++ks)
                av[ks] = *(const short8*)(&wvb[(w * 16 + lr) * 512 + h * 64 + ks * 32 + lq * 8]);
            float* W = Weff + b * 4096;
#pragma unroll
            for (int nt = 0; nt < 4; ++nt) {
                f32x4 acc = {0.f, 0.f, 0.f, 0.f};
#pragma unroll
                for (int ks = 0; ks < 2; ++ks) {
                    short8 bhi, blo;
#pragma unroll
                    for (int jj = 0; jj < 8; ++jj) {
                        short h16, l16;
                        splitbf(RA[(ks * 32 + lq * 8 + jj) * 68 + nt * 16 + lr], h16, l16);
                        bhi[jj] = h16; blo[jj] = l16;
                    }
                    acc = __builtin_amdgcn_mfma_f32_16x16x32_bf16(av[ks], bhi, acc, 0, 0, 0);
                    acc = __builtin_amdgcn_mfma_f32_16x16x32_bf16(av[ks], blo, acc, 0, 0, 0);
                }
#pragma unroll
                for (int r = 0; r < 4; ++r)
                    atomicAdd(&W[(w * 16 + lq * 4 + r) * 64 + nt * 16 + lr], acc[r]);
            }
        }
        return;
    }
    // ---- conv1 (proven round-4 body), cb = blk - 16 ----
    u16* sm = (u16*)shm;                       // 204*72 u16 = 29376 B
    int cb = blk - 16;
    int b  = cb >> 9;
    int ty = (cb >> 3) & 63;
    int tx = cb & 7;
    int gy0 = ty * 4, gx0 = tx * 32;

    for (int i = t; i < 1632; i += 256) {
        int px = i >> 3, ch = i & 7;
        int hy = px / 34, hx = px - hy * 34;
        int gy = gy0 + hy - 1, gx = gx0 + hx - 1;
        uint4 v = make_uint4(0, 0, 0, 0);
        if ((unsigned)gy < 256u && (unsigned)gx < 256u)
            v = *(const uint4*)(pbuf + ((size_t)((b << 16) + (gy << 8) + gx)) * 64 + ch * 8);
        *(uint4*)(&sm[px * 72 + ch * 8]) = v;
    }
    int oct = t & 7;
    float w[8][9];
#pragma unroll
    for (int j = 0; j < 8; ++j)
#pragma unroll
        for (int k = 0; k < 9; ++k) w[j][k] = bf2f(wpe1[(oct * 8 + j) * 9 + k]);
    __syncthreads();

#pragma unroll
    for (int s = 0; s < 4; ++s) {
        int lp = (t >> 3) + s * 32;
        int ly = lp >> 5, lx = lp & 31;
        float acc[8] = {0.f, 0.f, 0.f, 0.f, 0.f, 0.f, 0.f, 0.f};
#pragma unroll
        for (int dy = 0; dy < 3; ++dy)
#pragma unroll
            for (int dx = 0; dx < 3; ++dx) {
                int hp = (ly + dy) * 34 + lx + dx;
                uint4 v = *(const uint4*)(&sm[hp * 72 + oct * 8]);
                float f[8];
                unpack8(v, f);
                int tap = dy * 3 + dx;
#pragma unroll
                for (int j = 0; j < 8; ++j) acc[j] += f[j] * w[j][tap];
            }
        u32 pk[4];
#pragma unroll
        for (int q = 0; q < 4; ++q)
            pk[q] = pk2(gelu_exact(acc[2 * q]), gelu_exact(acc[2 * q + 1]));
        size_t gpix = (size_t)(b << 16) + ((size_t)(gy0 + ly) << 8) + gx0 + lx;
        *(uint4*)(tbuf + gpix * 64 + oct * 8) = make_uint4(pk[0], pk[1], pk[2], pk[3]);
    }
}

// ---------------------------------------------------------------------------
// K4: out = xb @ Weff[b] + bproj + dwconv3x3(tbuf, Wpe2) (proven round-4 body)
__global__ __launch_bounds__(256) void k_final(const u16* __restrict__ xb,
                                               const u16* __restrict__ tbuf,
                                               const float* __restrict__ Weff,
                                               const u16* __restrict__ wpe2,
                                               const u16* __restrict__ bproj,
                                               float* __restrict__ out) {
    __shared__ u16 sm[204 * 72];
    __shared__ float stage[128 * 68];
    int t = threadIdx.x;
    int blk = blockIdx.x;
    int b  = blk >> 9;
    int ty = (blk >> 3) & 63;
    int tx = blk & 7;
    int gy0 = ty * 4, gx0 = tx * 32;

    for (int i = t; i < 1632; i += 256) {
        int px = i >> 3, ch = i & 7;
        int hy = px / 34, hx = px - hy * 34;
        int gy = gy0 + hy - 1, gx = gx0 + hx - 1;
        uint4 v = make_uint4(0, 0, 0, 0);
        if ((unsigned)gy < 256u && (unsigned)gx < 256u)
            v = *(const uint4*)(tbuf + ((size_t)((b << 16) + (gy << 8) + gx)) * 64 + ch * 8);
        *(uint4*)(&sm[px * 72 + ch * 8]) = v;
    }
    int oct = t & 7;
    {
        float w[8][9];
#pragma unroll
        for (int j = 0; j < 8; ++j)
#pragma unroll
            for (int k = 0; k < 9; ++k) w[j][k] = bf2f(wpe2[(oct * 8 + j) * 9 + k]);
        __syncthreads();
#pragma unroll
        for (int s = 0; s < 4; ++s) {
            int lp = (t >> 3) + s * 32;
            int ly = lp >> 5, lx = lp & 31;
            float acc[8] = {0.f, 0.f, 0.f, 0.f, 0.f, 0.f, 0.f, 0.f};
#pragma unroll
            for (int dy = 0; dy < 3; ++dy)
#pragma unroll
                for (int dx = 0; dx < 3; ++dx) {
                    int hp = (ly + dy) * 34 + lx + dx;
                    uint4 v = *(const uint4*)(&sm[hp * 72 + oct * 8]);
                    float f[8];
                    unpack8(v, f);
                    int tap = dy * 3 + dx;
#pragma unroll
                    for (int j = 0; j < 8; ++j) acc[j] += f[j] * w[j][tap];
                }
#pragma unroll
            for (int j = 0; j < 8; ++j)
                stage[lp * 68 + oct * 8 + j] = acc[j];
        }
    }
    __syncthreads();

    int lane = t & 63, wv = t >> 6;
    int col = lane & 15, quad = lane >> 4;
    const float* W = Weff + b * 4096;
    short8 bf[2][4];
#pragma unroll
    for (int kh = 0; kh < 2; ++kh)
#pragma unroll
        for (int nt = 0; nt < 4; ++nt) {
            short8 v;
#pragma unroll
            for (int j = 0; j < 8; ++j)
                v[j] = (short)f2bf(W[(kh * 32 + quad * 8 + j) * 64 + nt * 16 + col]);
            bf[kh][nt] = v;
        }
    float bias[4];
#pragma unroll
    for (int nt = 0; nt < 4; ++nt) bias[nt] = bf2f(bproj[nt * 16 + col]);

#pragma unroll
    for (int g = 0; g < 2; ++g) {
        int grp = wv * 2 + g;
        int ly = grp >> 1;
        int lxb = (grp & 1) * 16;
        size_t rowpix = (size_t)(b << 16) + ((size_t)(gy0 + ly) << 8) + gx0;
        const short8* ap = (const short8*)(xb + (rowpix + lxb + col) * 64);
        short8 a0 = ap[quad];
        short8 a1 = ap[4 + quad];
#pragma unroll
        for (int nt = 0; nt < 4; ++nt) {
            f32x4 acc = {0.f, 0.f, 0.f, 0.f};
            acc = __builtin_amdgcn_mfma_f32_16x16x32_bf16(a0, bf[0][nt], acc, 0, 0, 0);
            acc = __builtin_amdgcn_mfma_f32_16x16x32_bf16(a1, bf[1][nt], acc, 0, 0, 0);
#pragma unroll
            for (int r = 0; r < 4; ++r) {
                int lp = ly * 32 + lxb + quad * 4 + r;
                stage[lp * 68 + nt * 16 + col] += acc[r] + bias[nt];
            }
        }
    }
    __syncthreads();

#pragma unroll
    for (int k = 0; k < 8; ++k) {
        int linear = k * 256 + t;
        int px = linear >> 4, c4 = linear & 15;
        int ly = px >> 5, lx = px & 31;
        float4 v = *(const float4*)(&stage[px * 68 + c4 * 4]);
        size_t gpix = (size_t)(b << 16) + ((size_t)(gy0 + ly) << 8) + gx0 + lx;
        *(float4*)(out + gpix * 64 + c4 * 4) = v;
    }
}

// ---------------------------------------------------------------------------
extern "C" void kernel_launch(void* const* d_in, const int* in_sizes, int n_in,
                              void* d_out, int out_size, void* d_ws, size_t ws_size,
                              hipStream_t stream) {
    const float* x = (const float*)d_in[0];
    float* out = (float*)d_out;

    char* w = (char*)d_ws;
    size_t off = 0;
    auto alloc = [&](size_t bytes) -> void* {
        void* p = w + off;
        off += (bytes + 255) & ~(size_t)255;
        return p;
    };
    u16* xb = (u16*)alloc((size_t)16777216 * 2);
    u16* wb = (u16*)alloc((size_t)165128 * 2);
    u16* wqb = wb;
    u16* wkb = wqb + 32768;
    u16* wvb = wkb + 32768;
    u16* rsb = wvb + 32768;
    u16* wpb = rsb + 8;
    u16* bpb = wpb + 32768;
    u16* wcb = bpb + 64;
    u16* bcb = wcb + 32768;
    u16* p1b = bcb + 64;
    u16* p2b = p1b + 576;
    (void)wcb; (void)wqb; (void)wkb; (void)wpb;

    u16* wqT = (u16*)alloc((size_t)32768 * 2);
    u16* wkT = (u16*)alloc((size_t)32768 * 2);
    u16* wpT = (u16*)alloc((size_t)32768 * 2);

    float* partials = (float*)alloc((size_t)512 * 4096 * 4);
    float* G4       = (float*)alloc((size_t)2 * 4 * 4096 * 4);
    float* Weff     = (float*)alloc((size_t)2 * 4096 * 4);
    float* Wpos     = (float*)alloc((size_t)4096 * 4);
    u16*   pbuf     = (u16*)alloc((size_t)2 * 65536 * 64 * 2);
    u16*   tbuf     = (u16*)alloc((size_t)2 * 65536 * 64 * 2);

    hipLaunchKernelGGL(k_front, dim3(899), dim3(256), 0, stream,
                       x,
                       (const float*)d_in[1], (const float*)d_in[2], (const float*)d_in[3],
                       (const float*)d_in[4], (const float*)d_in[5], (const float*)d_in[6],
                       (const float*)d_in[7], (const float*)d_in[8], (const float*)d_in[9],
                       (const float*)d_in[10],
                       (u32*)wb, wqT, wkT, wpT, Wpos, xb, partials);
    hipLaunchKernelGGL(k_mid1, dim3(1152), dim3(256), 0, stream,
                       partials, G4, Weff, xb, Wpos, bcb, pbuf);
    hipLaunchKernelGGL(k_mid2, dim3(1040), dim3(256), 0, stream,
                       wqT, wkT, wpT, wvb, rsb, G4, Weff, pbuf, p1b, tbuf);
    hipLaunchKernelGGL(k_final, dim3(1024), dim3(256), 0, stream,
                       xb, tbuf, Weff, p2b, bpb, out);
}